// Round 17
// baseline (132.547 us; speedup 1.0000x reference)
//
#include <hip/hip_runtime.h>
#include <math.h>

#define NB 8
#define NHH 32
#define NWW 32
#define NC 384
#define NHEAD 12
#define NHD 32
#define NN1 1025
#define NHW 1024
#define NMROWS (NB * NN1)   /* 8200 */
#define MPAD 8320           /* padded M for ao/proj (1025-based) */
#define NPB 1088            /* padded rows per batch (17*64) */
#define MP2 (NB * NPB)      /* 8704 padded global rows */
#define NMT (MP2 / 64)      /* 136 m-tiles */
#define CST 1152            /* canonical C row stride (cols) */
#define NBH (NB * NHEAD)    /* 96 */
#define QTILES 17           /* 64-row q tiles covering 1025 rows */

typedef float f32x4 __attribute__((ext_vector_type(4)));
typedef __bf16 bf16x8 __attribute__((ext_vector_type(8)));
typedef __bf16 bf16x4 __attribute__((ext_vector_type(4)));
typedef short s16x4 __attribute__((ext_vector_type(4)));
typedef __attribute__((address_space(3))) unsigned int lds_u32;
typedef const __attribute__((address_space(1))) unsigned int glb_u32;

static __device__ __forceinline__ bf16x8 as_bf16x8(uint4 u) {
    union { uint4 a; bf16x8 b; } x; x.a = u; return x.b;
}
static __device__ __forceinline__ unsigned short bfbits(__bf16 b) {
    union { __bf16 a; unsigned short s; } u; u.a = b; return u.s;
}
static __device__ __forceinline__ float bf2f(unsigned short s) {
    union { unsigned u; float f; } x; x.u = ((unsigned)s) << 16; return x.f;
}
static __device__ __forceinline__ unsigned pack2(float a, float b) {
    return (unsigned)bfbits((__bf16)a) | ((unsigned)bfbits((__bf16)b) << 16);
}
// native v_exp_f32 (plain -O3 lowers exp2f to slow precise OCML path)
static __device__ __forceinline__ float fexp2(float x) {
    return __builtin_amdgcn_exp2f(x);
}
static __device__ __forceinline__ f32x4 mfma16(bf16x4 a, bf16x4 b, f32x4 c) {
#if __has_builtin(__builtin_amdgcn_mfma_f32_16x16x16_bf16)
    return __builtin_amdgcn_mfma_f32_16x16x16_bf16(a, b, c, 0, 0, 0);
#else
    union { bf16x4 h; s16x4 s; } ua, ub; ua.h = a; ub.h = b;
    return __builtin_amdgcn_mfma_f32_16x16x16bf16_1k(ua.s, ub.s, c, 0, 0, 0);
#endif
}
// bijective XCD swizzle (m204)
static __device__ __forceinline__ int xcd_swz(int i, int nwg) {
    int xcd = i & 7, pos = i >> 3;
    int q = nwg >> 3, r = nwg & 7;
    return xcd * q + (xcd < r ? xcd : r) + pos;
}

// ---------------------------------------------------------------------------
// Kernel 0: prep (unchanged)
// ---------------------------------------------------------------------------
#define P_N1 835584
#define P_N2 110592
#define P_N3 36864
#define P_N4 9600
#define P_N5 11520
#define P_TOT (P_N1 + P_N2 + P_N3 + P_N4 + P_N5)

__global__ __launch_bounds__(256) void prep_k(
    const float* __restrict__ x, const float* __restrict__ cls,
    const float* __restrict__ qkv_w, const float* __restrict__ proj_w,
    const float* __restrict__ lepe_w,
    __bf16* __restrict__ Ab, __bf16* __restrict__ wqb, __bf16* __restrict__ wpb,
    float* __restrict__ lepeT, __bf16* __restrict__ aob)
{
    int idx = blockIdx.x * 256 + threadIdx.x;
    if (idx >= P_TOT) return;
    if (idx < P_N1) {
        int e0 = idx * 4;
        int mp = e0 / NC, kk = e0 % NC;
        int b = mp / NPB, n = mp % NPB;
        float4 v = make_float4(0.f, 0.f, 0.f, 0.f);
        if (n < NN1) {
            const float* src = (n == 0) ? (cls + (size_t)b * NC + kk)
                                        : (x + ((size_t)(b * NHW + (n - 1))) * NC + kk);
            v = *(const float4*)src;
        }
        uint2 u; u.x = pack2(v.x, v.y); u.y = pack2(v.z, v.w);
        *(uint2*)(Ab + (size_t)mp * NC + kk) = u;
        return;
    }
    idx -= P_N1;
    if (idx < P_N2) {
        int e0 = idx * 4;
        float4 v = *(const float4*)(qkv_w + e0);
        uint2 u; u.x = pack2(v.x, v.y); u.y = pack2(v.z, v.w);
        *(uint2*)(wqb + e0) = u;
        return;
    }
    idx -= P_N2;
    if (idx < P_N3) {
        int e0 = idx * 4;
        float4 v = *(const float4*)(proj_w + e0);
        uint2 u; u.x = pack2(v.x, v.y); u.y = pack2(v.z, v.w);
        *(uint2*)(wpb + e0) = u;
        return;
    }
    idx -= P_N3;
    if (idx < P_N4) {
        int tap = idx / NC, cc = idx % NC;
        lepeT[tap * NC + cc] = lepe_w[cc * 25 + tap];
        return;
    }
    idx -= P_N4;
    {
        uint2 z; z.x = 0; z.y = 0;
        *(uint2*)(aob + (size_t)NMROWS * NC + idx * 4) = z;
    }
}

#define LP 72
#define QSCALE 0.25505654007f   /* 1/sqrt(32) * log2(e) */
#define CPD 136

// ---------------------------------------------------------------------------
// QKV GEMM: gload_lds width-16 + XOR-swizzle (unchanged R13).
// ---------------------------------------------------------------------------
union QkvSm {
    struct { __bf16 As[2][64][64]; __bf16 Bs[2][128][64]; } g;
    __bf16 C[64][CPD];
};

__global__ __launch_bounds__(256) void qkv_mfma_k(
    const __bf16* __restrict__ A, const __bf16* __restrict__ W,
    __bf16* __restrict__ Cg)
{
    __shared__ QkvSm sm;
    const int tid  = threadIdx.x;
    const int lane = tid & 63;
    const int wid  = tid >> 6;
    const int wr   = wid >> 1, wc = wid & 1;
    const int c    = lane & 15, hg = lane >> 4;
    const int wg   = xcd_swz(blockIdx.x, 9 * NMT);
    const int tile = wg % 9;
    const int m0   = (wg / 9) * 64;
    const int n0   = tile * 128;

    int aw_row[2], aw_col[2];
#pragma unroll
    for (int j = 0; j < 2; ++j) {
        int word = (wid * 2 + j) * 64 + lane;
        int row = word >> 3, slot = word & 7;
        aw_row[j] = row;
        aw_col[j] = (slot ^ (row & 7)) * 8;
    }
    int bw_row[4], bw_col[4];
#pragma unroll
    for (int j = 0; j < 4; ++j) {
        int word = (wid * 4 + j) * 64 + lane;
        int row = word >> 3, slot = word & 7;
        bw_row[j] = row;
        bw_col[j] = (slot ^ (row & 7)) * 8;
    }

    f32x4 acc[2][4];
#pragma unroll
    for (int i = 0; i < 2; ++i)
#pragma unroll
        for (int j = 0; j < 4; ++j) acc[i][j] = f32x4{0.f, 0.f, 0.f, 0.f};

    __bf16* asbase = &sm.g.As[0][0][0];
    __bf16* bsbase = &sm.g.Bs[0][0][0];

    auto stage = [&](int buf, int k0) {
#pragma unroll
        for (int j = 0; j < 2; ++j) {
            const __bf16* src = A + (size_t)(m0 + aw_row[j]) * NC + k0 + aw_col[j];
            __bf16* dst = asbase + (size_t)buf * 4096 + (wid * 2 + j) * 512;
            __builtin_amdgcn_global_load_lds((glb_u32*)src, (lds_u32*)dst, 16, 0, 0);
        }
#pragma unroll
        for (int j = 0; j < 4; ++j) {
            const __bf16* src = W + (size_t)(n0 + bw_row[j]) * NC + k0 + bw_col[j];
            __bf16* dst = bsbase + (size_t)buf * 8192 + (wid * 4 + j) * 512;
            __builtin_amdgcn_global_load_lds((glb_u32*)src, (lds_u32*)dst, 16, 0, 0);
        }
    };

    stage(0, 0);
    __syncthreads();

    for (int t = 0; t < 6; ++t) {
        const int cur = t & 1;
        if (t < 5) stage(cur ^ 1, (t + 1) * 64);

        const __bf16* ab = asbase + (size_t)cur * 4096;
        const __bf16* bb = bsbase + (size_t)cur * 8192;
#pragma unroll
        for (int ks = 0; ks < 2; ++ks) {
            bf16x8 af[2], bfr[4];
#pragma unroll
            for (int i = 0; i < 2; ++i) {
                int row = wr * 32 + i * 16 + c;
                int slot = (ks * 4 + hg) ^ (row & 7);
                af[i] = as_bf16x8(*(const uint4*)(ab + row * 64 + slot * 8));
            }
#pragma unroll
            for (int j = 0; j < 4; ++j) {
                int row = wc * 64 + j * 16 + c;
                int slot = (ks * 4 + hg) ^ (row & 7);
                bfr[j] = as_bf16x8(*(const uint4*)(bb + row * 64 + slot * 8));
            }
            __builtin_amdgcn_s_setprio(1);
#pragma unroll
            for (int i = 0; i < 2; ++i)
#pragma unroll
                for (int j = 0; j < 4; ++j)
                    acc[i][j] = __builtin_amdgcn_mfma_f32_16x16x32_bf16(
                        af[i], bfr[j], acc[i][j], 0, 0, 0);
            __builtin_amdgcn_s_setprio(0);
        }
        if (t < 5) __syncthreads();
    }

    __syncthreads();
    const float qs = (tile < 3) ? QSCALE : 1.0f;
#pragma unroll
    for (int i = 0; i < 2; ++i)
#pragma unroll
        for (int r = 0; r < 4; ++r) {
            int row = wr * 32 + i * 16 + 4 * hg + r;
#pragma unroll
            for (int j = 0; j < 4; ++j)
                sm.C[row][wc * 64 + j * 16 + c] = (__bf16)(acc[i][j][r] * qs);
        }
    __syncthreads();

#pragma unroll
    for (int it = 0; it < 4; ++it) {
        int idx   = it * 256 + tid;
        int row   = idx >> 4;
        int chunk = idx & 15;
        uint4 u = *(const uint4*)&sm.C[row][chunk * 8];
        *(uint4*)(Cg + (size_t)(m0 + row) * CST + n0 + chunk * 8) = u;
    }
}

// ---------------------------------------------------------------------------
// proj GEMM (unchanged).
// ---------------------------------------------------------------------------
__global__ __launch_bounds__(256) void proj_mfma_k(
    const __bf16* __restrict__ A, const __bf16* __restrict__ W,
    const float* __restrict__ bias, float* __restrict__ out)
{
    __shared__ __bf16 As[128][LP];
    __shared__ __bf16 Bs[64][LP];
    const int tid  = threadIdx.x;
    const int lane = tid & 63;
    const int wid  = tid >> 6;
    const int wr   = wid >> 1, wc = wid & 1;
    const int c    = lane & 15, hg = lane >> 4;
    const int wg   = xcd_swz(blockIdx.x, 6 * 65);
    const int m0   = (wg / 6) * 128;
    const int n0   = (wg % 6) * 64;
    const int srow = tid >> 1;
    const int scol = (tid & 1) * 32;
    const int brow = tid >> 2;
    const int bcol = (tid & 3) * 16;

    f32x4 acc[4][2];
#pragma unroll
    for (int i = 0; i < 4; ++i)
#pragma unroll
        for (int j = 0; j < 2; ++j) acc[i][j] = f32x4{0.f, 0.f, 0.f, 0.f};

    uint4 a4[4], b4[2];
#pragma unroll
    for (int s = 0; s < 4; ++s)
        a4[s] = *(const uint4*)(A + (size_t)(m0 + srow) * NC + scol + s * 8);
#pragma unroll
    for (int s = 0; s < 2; ++s)
        b4[s] = *(const uint4*)(W + (size_t)(n0 + brow) * NC + bcol + s * 8);

    for (int k0 = 0; k0 < NC; k0 += 64) {
        __syncthreads();
#pragma unroll
        for (int s = 0; s < 4; ++s) *(uint4*)&As[srow][scol + s * 8] = a4[s];
#pragma unroll
        for (int s = 0; s < 2; ++s) *(uint4*)&Bs[brow][bcol + s * 8] = b4[s];
        __syncthreads();
        if (k0 + 64 < NC) {
#pragma unroll
            for (int s = 0; s < 4; ++s)
                a4[s] = *(const uint4*)(A + (size_t)(m0 + srow) * NC + k0 + 64 + scol + s * 8);
#pragma unroll
            for (int s = 0; s < 2; ++s)
                b4[s] = *(const uint4*)(W + (size_t)(n0 + brow) * NC + k0 + 64 + bcol + s * 8);
        }
#pragma unroll
        for (int ks = 0; ks < 2; ++ks) {
            bf16x8 af[4], bfr[2];
#pragma unroll
            for (int i = 0; i < 4; ++i)
                af[i] = as_bf16x8(*(const uint4*)&As[wr * 64 + i * 16 + c][ks * 32 + hg * 8]);
#pragma unroll
            for (int j = 0; j < 2; ++j)
                bfr[j] = as_bf16x8(*(const uint4*)&Bs[wc * 32 + j * 16 + c][ks * 32 + hg * 8]);
#pragma unroll
            for (int i = 0; i < 4; ++i)
#pragma unroll
                for (int j = 0; j < 2; ++j)
                    acc[i][j] = __builtin_amdgcn_mfma_f32_16x16x32_bf16(
                        af[i], bfr[j], acc[i][j], 0, 0, 0);
        }
    }

#pragma unroll
    for (int i = 0; i < 4; ++i)
#pragma unroll
        for (int r = 0; r < 4; ++r) {
            int m = m0 + wr * 64 + i * 16 + 4 * hg + r;
            if (m >= NMROWS) continue;
            int b = m / NN1, n = m % NN1;
            float* dstrow = (n == 0)
                ? (out + (size_t)NB * NHW * NC + (size_t)b * NC)
                : (out + ((size_t)(b * NHW) + (n - 1)) * NC);
#pragma unroll
            for (int j = 0; j < 2; ++j) {
                int col = n0 + wc * 32 + j * 16 + c;
                dstrow[col] = acc[i][j][r] + bias[col];
            }
        }
}

// ---------------------------------------------------------------------------
// Kernel 2: flash attention, 64-row q-tiles (16 rows/wave), grid 1632 blocks
// for wave-level overlap of the VALU-heavy softmax.  K register-prefetched,
// P in registers, Vs-only LDS, native exp2.
// ---------------------------------------------------------------------------
#define KC 64
#define VPAD 72
#define NCH ((NN1 + KC - 1) / KC)   /* 17 */

__global__ __launch_bounds__(256) void attn_mfma_k(
    const __bf16* __restrict__ Cg, __bf16* __restrict__ ao)
{
    __shared__ unsigned short Vs[2][32][VPAD];

    const int wg    = xcd_swz(blockIdx.x, QTILES * NBH);
    const int qtile = wg % QTILES;
    const int bh    = wg / QTILES;
    const int b     = bh / NHEAD;
    const int hh    = bh % NHEAD;
    const int tid   = threadIdx.x;
    const int lane  = tid & 63;
    const int wv    = tid >> 6;
    const int c     = lane & 15;
    const int hg    = lane >> 4;
    const int q0    = qtile * 64 + wv * 16;
    const size_t MBp = (size_t)b * NPB;

    const __bf16* qb = Cg + hh * 32;
    const __bf16* kb = Cg + 384 + hh * 32;
    const __bf16* vb = Cg + 768 + hh * 32;

    uint4 zero4 = make_uint4(0, 0, 0, 0);
    bf16x8 qf;
    {
        int row = q0 + c;
        uint4 u = (row < NN1)
            ? *(const uint4*)(qb + (MBp + row) * CST + hg * 8) : zero4;
        qf = as_bf16x8(u);
    }

    f32x4 O[2];
#pragma unroll
    for (int dt = 0; dt < 2; ++dt) O[dt] = f32x4{0.f, 0.f, 0.f, 0.f};
    float lrun = 0.f;

    const int k_row = tid >> 2;
    const int k_col = (tid & 3) * 8;

    uint4 kcur[4], knxt[4];
#pragma unroll
    for (int kt = 0; kt < 4; ++kt)
        kcur[kt] = *(const uint4*)(kb + (MBp + kt * 16 + c) * CST + hg * 8);
    uint4 vr = *(const uint4*)(vb + (MBp + k_row) * CST + k_col);
    {
        union { uint4 u; unsigned short s[8]; } vu; vu.u = vr;
#pragma unroll
        for (int j = 0; j < 8; ++j) Vs[0][k_col + j][k_row] = vu.s[j];
    }
    __syncthreads();

    for (int t = 0; t < NCH; ++t) {
        const int kt0 = t * KC;
        const int cur = t & 1;
        const bool haveNext = (t + 1 < NCH);
        if (haveNext) {
#pragma unroll
            for (int kt = 0; kt < 4; ++kt)
                knxt[kt] = *(const uint4*)(kb + (MBp + kt0 + KC + kt * 16 + c) * CST + hg * 8);
            vr = *(const uint4*)(vb + (MBp + kt0 + KC + k_row) * CST + k_col);
        }
        const bool full = (kt0 + KC <= NN1);

        // ---- QK^T + softmax -> in-register P ----
        f32x4 Sf[4];
        __builtin_amdgcn_s_setprio(1);
#pragma unroll
        for (int kt = 0; kt < 4; ++kt)
            Sf[kt] = __builtin_amdgcn_mfma_f32_16x16x32_bf16(
                as_bf16x8(kcur[kt]), qf, f32x4{0.f, 0.f, 0.f, 0.f}, 0, 0, 0);
        __builtin_amdgcn_s_setprio(0);

        if (!full) {   // mask pad keys (exp2(-3e38)==0)
#pragma unroll
            for (int kt = 0; kt < 4; ++kt)
#pragma unroll
                for (int r = 0; r < 4; ++r) {
                    int key = kt0 + kt * 16 + 4 * hg + r;
                    if (key >= NN1) Sf[kt][r] = -3.0e38f;
                }
        }
        bf16x4 pa[4];
        float psum = 0.f;
#pragma unroll
        for (int kt = 0; kt < 4; ++kt) {
            float p0 = fexp2(Sf[kt][0]);
            float p1 = fexp2(Sf[kt][1]);
            float p2 = fexp2(Sf[kt][2]);
            float p3 = fexp2(Sf[kt][3]);
            psum += (p0 + p1) + (p2 + p3);
            pa[kt] = bf16x4{(__bf16)p0, (__bf16)p1, (__bf16)p2, (__bf16)p3};
        }
        lrun += psum;

        // ---- V B-frags + PV via 16x16x16 ----
        bf16x4 vbf[2][4];
#pragma unroll
        for (int dt = 0; dt < 2; ++dt)
#pragma unroll
            for (int kt = 0; kt < 4; ++kt)
                vbf[dt][kt] = *(const bf16x4*)&Vs[cur][dt * 16 + c][kt * 16 + 4 * hg];

        __builtin_amdgcn_s_setprio(1);
#pragma unroll
        for (int dt = 0; dt < 2; ++dt)
#pragma unroll
            for (int kt = 0; kt < 4; ++kt)
                O[dt] = mfma16(pa[kt], vbf[dt][kt], O[dt]);
        __builtin_amdgcn_s_setprio(0);

        if (haveNext) {
            union { uint4 u; unsigned short s[8]; } vu; vu.u = vr;
#pragma unroll
            for (int j = 0; j < 8; ++j) Vs[cur ^ 1][k_col + j][k_row] = vu.s[j];
#pragma unroll
            for (int kt = 0; kt < 4; ++kt) kcur[kt] = knxt[kt];
            __syncthreads();
        }
    }

    // epilogue: reduce partial l across hg groups, normalize, store
    {
        float Ls = lrun;
        Ls += __shfl_xor(Ls, 16);
        Ls += __shfl_xor(Ls, 32);
#pragma unroll
        for (int r = 0; r < 4; ++r) {
            float lr_ = __shfl(Ls, 4 * hg + r);
            int row = q0 + 4 * hg + r;
            float inv = (lr_ > 0.f) ? 1.0f / lr_ : 0.f;
            if (row < NN1) {
#pragma unroll
                for (int dt = 0; dt < 2; ++dt)
                    ao[((size_t)(b * NN1 + row)) * NC + hh * NHD + dt * 16 + c]
                        = (__bf16)(O[dt][r] * inv);
            }
        }
    }
}

// ---------------------------------------------------------------------------
// Kernel 3: LePE depthwise 5x5 conv (unchanged).
// ---------------------------------------------------------------------------
__global__ __launch_bounds__(256) void lepe2_k(
    const float* __restrict__ x, const float* __restrict__ wT,
    const float* __restrict__ bias, __bf16* __restrict__ ao)
{
    int idx = blockIdx.x * 256 + threadIdx.x;
    if (idx >= NB * (NHH / 2) * NWW * (NC / 4)) return;
    int cg = idx % (NC / 4);
    int c4 = cg * 4;
    int pos = idx / (NC / 4);
    int ww = pos % NWW;
    int hp = (pos / NWW) % (NHH / 2);
    int b = pos / (NWW * (NHH / 2));
    int hh = hp * 2;

    float4 bv = *(const float4*)(bias + c4);
    float a0[2], a1[2], a2[2], a3[2];
    a0[0] = bv.x; a1[0] = bv.y; a2[0] = bv.z; a3[0] = bv.w;
    a0[1] = bv.x; a1[1] = bv.y; a2[1] = bv.z; a3[1] = bv.w;

#pragma unroll
    for (int i = 0; i < 6; ++i) {
        int y = hh + i - 2;
        bool yv = (unsigned)y < NHH;
#pragma unroll
        for (int j = 0; j < 5; ++j) {
            int xw = ww + j - 2;
            if (yv && (unsigned)xw < NWW) {
                float4 xv = *(const float4*)(x + (((size_t)b * NHH + y) * NWW + xw) * NC + c4);
                if (i < 5) {
                    float4 wv = *(const float4*)(wT + (i * 5 + j) * NC + c4);
                    a0[0] += xv.x * wv.x; a1[0] += xv.y * wv.y;
                    a2[0] += xv.z * wv.z; a3[0] += xv.w * wv.w;
                }
                if (i >= 1) {
                    float4 wv = *(const float4*)(wT + ((i - 1) * 5 + j) * NC + c4);
                    a0[1] += xv.x * wv.x; a1[1] += xv.y * wv.y;
                    a2[1] += xv.z * wv.z; a3[1] += xv.w * wv.w;
                }
            }
        }
    }

#pragma unroll
    for (int rr = 0; rr < 2; ++rr) {
        size_t m = (size_t)b * NN1 + 1 + (hh + rr) * NWW + ww;
        uint2* aop = (uint2*)(ao + m * NC + c4);
        uint2 old = *aop;
        float r0 = a0[rr] + bf2f((unsigned short)(old.x & 0xffff));
        float r1 = a1[rr] + bf2f((unsigned short)(old.x >> 16));
        float r2 = a2[rr] + bf2f((unsigned short)(old.y & 0xffff));
        float r3 = a3[rr] + bf2f((unsigned short)(old.y >> 16));
        uint2 nw; nw.x = pack2(r0, r1); nw.y = pack2(r2, r3);
        *aop = nw;
    }
}

// ---------------------------------------------------------------------------
extern "C" void kernel_launch(void* const* d_in, const int* in_sizes, int n_in,
                              void* d_out, int out_size, void* d_ws, size_t ws_size,
                              hipStream_t stream)
{
    const float* x      = (const float*)d_in[0];
    const float* cls    = (const float*)d_in[1];
    const float* qkv_w  = (const float*)d_in[2];
    const float* proj_w = (const float*)d_in[3];
    const float* proj_b = (const float*)d_in[4];
    const float* lepe_w = (const float*)d_in[5];
    const float* lepe_b = (const float*)d_in[6];
    float* out = (float*)d_out;
    char*  ws  = (char*)d_ws;

    size_t off = 0;
    __bf16* Ab    = (__bf16*)(ws + off); off += (size_t)MP2 * NC * 2;
    __bf16* wqb   = (__bf16*)(ws + off); off += (size_t)1152 * NC * 2;
    __bf16* wpb   = (__bf16*)(ws + off); off += (size_t)NC * NC * 2;
    float*  lepeT = (float*) (ws + off); off += (size_t)25 * NC * 4;
    __bf16* Cg    = (__bf16*)(ws + off); off += (size_t)MP2 * CST * 2;
    __bf16* aob   = (__bf16*)(ws + off); off += (size_t)MPAD * NC * 2;

    {   // prep
        prep_k<<<(P_TOT + 255) / 256, 256, 0, stream>>>(
            x, cls, qkv_w, proj_w, lepe_w, Ab, wqb, wpb, lepeT, aob);
    }
    {   // QKV GEMM: gload_lds + swizzle, 1224 blocks
        qkv_mfma_k<<<9 * NMT, 256, 0, stream>>>(Ab, wqb, Cg);
    }
    {   // flash attention: 1632 blocks (64-row q tiles)
        attn_mfma_k<<<QTILES * NBH, 256, 0, stream>>>(Cg, aob);
    }
    {   // LePE conv
        int total = NB * (NHW / 2) * (NC / 4);
        lepe2_k<<<(total + 255) / 256, 256, 0, stream>>>(x, lepeT, lepe_b, aob);
    }
    {   // projection GEMM
        proj_mfma_k<<<6 * 65, 256, 0, stream>>>(aob, wpb, proj_b, out);
    }
}

// Round 18
// 113.595 us; speedup vs baseline: 1.1668x; 1.1668x over previous
//
#include <hip/hip_runtime.h>
#include <math.h>

#define NB 8
#define NHH 32
#define NWW 32
#define NC 384
#define NHEAD 12
#define NHD 32
#define NN1 1025
#define NHW 1024
#define NMROWS (NB * NN1)   /* 8200 */
#define MPAD 8320           /* padded M for ao/proj (1025-based) */
#define NPB 1088            /* padded rows per batch (17*64) */
#define MP2 (NB * NPB)      /* 8704 padded global rows */
#define NMT (MP2 / 64)      /* 136 m-tiles */
#define CST 1152            /* canonical C row stride (cols) */
#define NBH (NB * NHEAD)    /* 96 */

typedef float f32x4 __attribute__((ext_vector_type(4)));
typedef __bf16 bf16x8 __attribute__((ext_vector_type(8)));
typedef __bf16 bf16x4 __attribute__((ext_vector_type(4)));
typedef short s16x4 __attribute__((ext_vector_type(4)));
typedef __attribute__((address_space(3))) unsigned int lds_u32;
typedef const __attribute__((address_space(1))) unsigned int glb_u32;

static __device__ __forceinline__ bf16x8 as_bf16x8(uint4 u) {
    union { uint4 a; bf16x8 b; } x; x.a = u; return x.b;
}
static __device__ __forceinline__ unsigned short bfbits(__bf16 b) {
    union { __bf16 a; unsigned short s; } u; u.a = b; return u.s;
}
static __device__ __forceinline__ float bf2f(unsigned short s) {
    union { unsigned u; float f; } x; x.u = ((unsigned)s) << 16; return x.f;
}
static __device__ __forceinline__ unsigned pack2(float a, float b) {
    return (unsigned)bfbits((__bf16)a) | ((unsigned)bfbits((__bf16)b) << 16);
}
// native v_exp_f32 (plain -O3 lowers exp2f to slow precise OCML path)
static __device__ __forceinline__ float fexp2(float x) {
    return __builtin_amdgcn_exp2f(x);
}
static __device__ __forceinline__ f32x4 mfma16(bf16x4 a, bf16x4 b, f32x4 c) {
#if __has_builtin(__builtin_amdgcn_mfma_f32_16x16x16_bf16)
    return __builtin_amdgcn_mfma_f32_16x16x16_bf16(a, b, c, 0, 0, 0);
#else
    union { bf16x4 h; s16x4 s; } ua, ub; ua.h = a; ub.h = b;
    return __builtin_amdgcn_mfma_f32_16x16x16bf16_1k(ua.s, ub.s, c, 0, 0, 0);
#endif
}
// bijective XCD swizzle (m204)
static __device__ __forceinline__ int xcd_swz(int i, int nwg) {
    int xcd = i & 7, pos = i >> 3;
    int q = nwg >> 3, r = nwg & 7;
    return xcd * q + (xcd < r ? xcd : r) + pos;
}

// ---------------------------------------------------------------------------
// Kernel 0: prep (unchanged)
// ---------------------------------------------------------------------------
#define P_N1 835584
#define P_N2 110592
#define P_N3 36864
#define P_N4 9600
#define P_N5 11520
#define P_TOT (P_N1 + P_N2 + P_N3 + P_N4 + P_N5)

__global__ __launch_bounds__(256) void prep_k(
    const float* __restrict__ x, const float* __restrict__ cls,
    const float* __restrict__ qkv_w, const float* __restrict__ proj_w,
    const float* __restrict__ lepe_w,
    __bf16* __restrict__ Ab, __bf16* __restrict__ wqb, __bf16* __restrict__ wpb,
    float* __restrict__ lepeT, __bf16* __restrict__ aob)
{
    int idx = blockIdx.x * 256 + threadIdx.x;
    if (idx >= P_TOT) return;
    if (idx < P_N1) {
        int e0 = idx * 4;
        int mp = e0 / NC, kk = e0 % NC;
        int b = mp / NPB, n = mp % NPB;
        float4 v = make_float4(0.f, 0.f, 0.f, 0.f);
        if (n < NN1) {
            const float* src = (n == 0) ? (cls + (size_t)b * NC + kk)
                                        : (x + ((size_t)(b * NHW + (n - 1))) * NC + kk);
            v = *(const float4*)src;
        }
        uint2 u; u.x = pack2(v.x, v.y); u.y = pack2(v.z, v.w);
        *(uint2*)(Ab + (size_t)mp * NC + kk) = u;
        return;
    }
    idx -= P_N1;
    if (idx < P_N2) {
        int e0 = idx * 4;
        float4 v = *(const float4*)(qkv_w + e0);
        uint2 u; u.x = pack2(v.x, v.y); u.y = pack2(v.z, v.w);
        *(uint2*)(wqb + e0) = u;
        return;
    }
    idx -= P_N2;
    if (idx < P_N3) {
        int e0 = idx * 4;
        float4 v = *(const float4*)(proj_w + e0);
        uint2 u; u.x = pack2(v.x, v.y); u.y = pack2(v.z, v.w);
        *(uint2*)(wpb + e0) = u;
        return;
    }
    idx -= P_N3;
    if (idx < P_N4) {
        int tap = idx / NC, cc = idx % NC;
        lepeT[tap * NC + cc] = lepe_w[cc * 25 + tap];
        return;
    }
    idx -= P_N4;
    {
        uint2 z; z.x = 0; z.y = 0;
        *(uint2*)(aob + (size_t)NMROWS * NC + idx * 4) = z;
    }
}

#define LP 72
#define QSCALE 0.25505654007f   /* 1/sqrt(32) * log2(e) */
#define CPD 136

// ---------------------------------------------------------------------------
// QKV GEMM: gload_lds width-16 + XOR-swizzle (unchanged R13).
// ---------------------------------------------------------------------------
union QkvSm {
    struct { __bf16 As[2][64][64]; __bf16 Bs[2][128][64]; } g;
    __bf16 C[64][CPD];
};

__global__ __launch_bounds__(256) void qkv_mfma_k(
    const __bf16* __restrict__ A, const __bf16* __restrict__ W,
    __bf16* __restrict__ Cg)
{
    __shared__ QkvSm sm;
    const int tid  = threadIdx.x;
    const int lane = tid & 63;
    const int wid  = tid >> 6;
    const int wr   = wid >> 1, wc = wid & 1;
    const int c    = lane & 15, hg = lane >> 4;
    const int wg   = xcd_swz(blockIdx.x, 9 * NMT);
    const int tile = wg % 9;
    const int m0   = (wg / 9) * 64;
    const int n0   = tile * 128;

    int aw_row[2], aw_col[2];
#pragma unroll
    for (int j = 0; j < 2; ++j) {
        int word = (wid * 2 + j) * 64 + lane;
        int row = word >> 3, slot = word & 7;
        aw_row[j] = row;
        aw_col[j] = (slot ^ (row & 7)) * 8;
    }
    int bw_row[4], bw_col[4];
#pragma unroll
    for (int j = 0; j < 4; ++j) {
        int word = (wid * 4 + j) * 64 + lane;
        int row = word >> 3, slot = word & 7;
        bw_row[j] = row;
        bw_col[j] = (slot ^ (row & 7)) * 8;
    }

    f32x4 acc[2][4];
#pragma unroll
    for (int i = 0; i < 2; ++i)
#pragma unroll
        for (int j = 0; j < 4; ++j) acc[i][j] = f32x4{0.f, 0.f, 0.f, 0.f};

    __bf16* asbase = &sm.g.As[0][0][0];
    __bf16* bsbase = &sm.g.Bs[0][0][0];

    auto stage = [&](int buf, int k0) {
#pragma unroll
        for (int j = 0; j < 2; ++j) {
            const __bf16* src = A + (size_t)(m0 + aw_row[j]) * NC + k0 + aw_col[j];
            __bf16* dst = asbase + (size_t)buf * 4096 + (wid * 2 + j) * 512;
            __builtin_amdgcn_global_load_lds((glb_u32*)src, (lds_u32*)dst, 16, 0, 0);
        }
#pragma unroll
        for (int j = 0; j < 4; ++j) {
            const __bf16* src = W + (size_t)(n0 + bw_row[j]) * NC + k0 + bw_col[j];
            __bf16* dst = bsbase + (size_t)buf * 8192 + (wid * 4 + j) * 512;
            __builtin_amdgcn_global_load_lds((glb_u32*)src, (lds_u32*)dst, 16, 0, 0);
        }
    };

    stage(0, 0);
    __syncthreads();

    for (int t = 0; t < 6; ++t) {
        const int cur = t & 1;
        if (t < 5) stage(cur ^ 1, (t + 1) * 64);

        const __bf16* ab = asbase + (size_t)cur * 4096;
        const __bf16* bb = bsbase + (size_t)cur * 8192;
#pragma unroll
        for (int ks = 0; ks < 2; ++ks) {
            bf16x8 af[2], bfr[4];
#pragma unroll
            for (int i = 0; i < 2; ++i) {
                int row = wr * 32 + i * 16 + c;
                int slot = (ks * 4 + hg) ^ (row & 7);
                af[i] = as_bf16x8(*(const uint4*)(ab + row * 64 + slot * 8));
            }
#pragma unroll
            for (int j = 0; j < 4; ++j) {
                int row = wc * 64 + j * 16 + c;
                int slot = (ks * 4 + hg) ^ (row & 7);
                bfr[j] = as_bf16x8(*(const uint4*)(bb + row * 64 + slot * 8));
            }
            __builtin_amdgcn_s_setprio(1);
#pragma unroll
            for (int i = 0; i < 2; ++i)
#pragma unroll
                for (int j = 0; j < 4; ++j)
                    acc[i][j] = __builtin_amdgcn_mfma_f32_16x16x32_bf16(
                        af[i], bfr[j], acc[i][j], 0, 0, 0);
            __builtin_amdgcn_s_setprio(0);
        }
        if (t < 5) __syncthreads();
    }

    __syncthreads();
    const float qs = (tile < 3) ? QSCALE : 1.0f;
#pragma unroll
    for (int i = 0; i < 2; ++i)
#pragma unroll
        for (int r = 0; r < 4; ++r) {
            int row = wr * 32 + i * 16 + 4 * hg + r;
#pragma unroll
            for (int j = 0; j < 4; ++j)
                sm.C[row][wc * 64 + j * 16 + c] = (__bf16)(acc[i][j][r] * qs);
        }
    __syncthreads();

#pragma unroll
    for (int it = 0; it < 4; ++it) {
        int idx   = it * 256 + tid;
        int row   = idx >> 4;
        int chunk = idx & 15;
        uint4 u = *(const uint4*)&sm.C[row][chunk * 8];
        *(uint4*)(Cg + (size_t)(m0 + row) * CST + n0 + chunk * 8) = u;
    }
}

// ---------------------------------------------------------------------------
// proj GEMM (unchanged).
// ---------------------------------------------------------------------------
__global__ __launch_bounds__(256) void proj_mfma_k(
    const __bf16* __restrict__ A, const __bf16* __restrict__ W,
    const float* __restrict__ bias, float* __restrict__ out)
{
    __shared__ __bf16 As[128][LP];
    __shared__ __bf16 Bs[64][LP];
    const int tid  = threadIdx.x;
    const int lane = tid & 63;
    const int wid  = tid >> 6;
    const int wr   = wid >> 1, wc = wid & 1;
    const int c    = lane & 15, hg = lane >> 4;
    const int wg   = xcd_swz(blockIdx.x, 6 * 65);
    const int m0   = (wg / 6) * 128;
    const int n0   = (wg % 6) * 64;
    const int srow = tid >> 1;
    const int scol = (tid & 1) * 32;
    const int brow = tid >> 2;
    const int bcol = (tid & 3) * 16;

    f32x4 acc[4][2];
#pragma unroll
    for (int i = 0; i < 4; ++i)
#pragma unroll
        for (int j = 0; j < 2; ++j) acc[i][j] = f32x4{0.f, 0.f, 0.f, 0.f};

    uint4 a4[4], b4[2];
#pragma unroll
    for (int s = 0; s < 4; ++s)
        a4[s] = *(const uint4*)(A + (size_t)(m0 + srow) * NC + scol + s * 8);
#pragma unroll
    for (int s = 0; s < 2; ++s)
        b4[s] = *(const uint4*)(W + (size_t)(n0 + brow) * NC + bcol + s * 8);

    for (int k0 = 0; k0 < NC; k0 += 64) {
        __syncthreads();
#pragma unroll
        for (int s = 0; s < 4; ++s) *(uint4*)&As[srow][scol + s * 8] = a4[s];
#pragma unroll
        for (int s = 0; s < 2; ++s) *(uint4*)&Bs[brow][bcol + s * 8] = b4[s];
        __syncthreads();
        if (k0 + 64 < NC) {
#pragma unroll
            for (int s = 0; s < 4; ++s)
                a4[s] = *(const uint4*)(A + (size_t)(m0 + srow) * NC + k0 + 64 + scol + s * 8);
#pragma unroll
            for (int s = 0; s < 2; ++s)
                b4[s] = *(const uint4*)(W + (size_t)(n0 + brow) * NC + k0 + 64 + bcol + s * 8);
        }
#pragma unroll
        for (int ks = 0; ks < 2; ++ks) {
            bf16x8 af[4], bfr[2];
#pragma unroll
            for (int i = 0; i < 4; ++i)
                af[i] = as_bf16x8(*(const uint4*)&As[wr * 64 + i * 16 + c][ks * 32 + hg * 8]);
#pragma unroll
            for (int j = 0; j < 2; ++j)
                bfr[j] = as_bf16x8(*(const uint4*)&Bs[wc * 32 + j * 16 + c][ks * 32 + hg * 8]);
#pragma unroll
            for (int i = 0; i < 4; ++i)
#pragma unroll
                for (int j = 0; j < 2; ++j)
                    acc[i][j] = __builtin_amdgcn_mfma_f32_16x16x32_bf16(
                        af[i], bfr[j], acc[i][j], 0, 0, 0);
        }
    }

#pragma unroll
    for (int i = 0; i < 4; ++i)
#pragma unroll
        for (int r = 0; r < 4; ++r) {
            int m = m0 + wr * 64 + i * 16 + 4 * hg + r;
            if (m >= NMROWS) continue;
            int b = m / NN1, n = m % NN1;
            float* dstrow = (n == 0)
                ? (out + (size_t)NB * NHW * NC + (size_t)b * NC)
                : (out + ((size_t)(b * NHW) + (n - 1)) * NC);
#pragma unroll
            for (int j = 0; j < 2; ++j) {
                int col = n0 + wc * 32 + j * 16 + c;
                dstrow[col] = acc[i][j][r] + bias[col];
            }
        }
}

// ---------------------------------------------------------------------------
// Kernel 2: flash attention, R16 structure (128-row q tiles) with key-chunk
// PAIRS per barrier: V double-buffered at 128-key granularity (9 barriers
// instead of 17).  K register-prefetched per sub-chunk.  VPAD=68 (136B rows)
// reduces transpose-write bank conflicts 8-way -> ~4-way.
// ---------------------------------------------------------------------------
#define KC 64
#define VPAD 68
#define NCH 17

__global__ __launch_bounds__(256) void attn_mfma_k(
    const __bf16* __restrict__ Cg, __bf16* __restrict__ ao)
{
    __shared__ unsigned short Vs[2][2][32][VPAD];   // [buf][sub][d][key] 17.4KB

    const int wg    = xcd_swz(blockIdx.x, 9 * NBH);
    const int qtile = wg % 9;
    const int bh    = wg / 9;
    const int b     = bh / NHEAD;
    const int hh    = bh % NHEAD;
    const int tid   = threadIdx.x;
    const int lane  = tid & 63;
    const int wv    = tid >> 6;
    const int c     = lane & 15;
    const int hg    = lane >> 4;
    const int q0    = qtile * 128 + wv * 32;
    const size_t MBp = (size_t)b * NPB;

    const __bf16* qb = Cg + hh * 32;
    const __bf16* kb = Cg + 384 + hh * 32;
    const __bf16* vb = Cg + 768 + hh * 32;

    uint4 zero4 = make_uint4(0, 0, 0, 0);
    bf16x8 qf[2];
#pragma unroll
    for (int qt = 0; qt < 2; ++qt) {
        int row = q0 + qt * 16 + c;
        uint4 u = (row < NN1)
            ? *(const uint4*)(qb + (MBp + row) * CST + hg * 8) : zero4;
        qf[qt] = as_bf16x8(u);
    }

    f32x4 O[2][2];
#pragma unroll
    for (int qt = 0; qt < 2; ++qt)
#pragma unroll
        for (int dt = 0; dt < 2; ++dt) O[qt][dt] = f32x4{0.f, 0.f, 0.f, 0.f};
    float lrun[2] = {0.f, 0.f};

    const int k_row = tid >> 2;          // key owned for V staging (0..63)
    const int k_col = (tid & 3) * 8;     // d0

    // prologue: K chunk 0 into regs; V chunks 0,1 into buf 0
    uint4 kcur[4], knxt[4];
#pragma unroll
    for (int kt = 0; kt < 4; ++kt)
        kcur[kt] = *(const uint4*)(kb + (MBp + kt * 16 + c) * CST + hg * 8);
    uint4 vr0 = *(const uint4*)(vb + (MBp + k_row) * CST + k_col);
    uint4 vr1 = *(const uint4*)(vb + (MBp + KC + k_row) * CST + k_col);
    {
        union { uint4 u; unsigned short s[8]; } vu;
        vu.u = vr0;
#pragma unroll
        for (int j = 0; j < 8; ++j) Vs[0][0][k_col + j][k_row] = vu.s[j];
        vu.u = vr1;
#pragma unroll
        for (int j = 0; j < 8; ++j) Vs[0][1][k_col + j][k_row] = vu.s[j];
    }
    __syncthreads();

    for (int to = 0; to < 9; ++to) {
        const int cur = to & 1;
        const bool havePair = (to < 8);
        if (havePair) {   // prefetch next V pair (chunks 2to+2, 2to+3)
            int tA = 2 * to + 2, tB = 2 * to + 3;
            vr0 = *(const uint4*)(vb + (MBp + tA * KC + k_row) * CST + k_col);
            vr1 = (tB < NCH)
                ? *(const uint4*)(vb + (MBp + tB * KC + k_row) * CST + k_col)
                : zero4;
        }

        for (int sub = 0; sub < 2; ++sub) {
            const int t = 2 * to + sub;
            if (t >= NCH) break;
            const int kt0 = t * KC;
            const bool haveK = (t + 1 < NCH);
            if (haveK) {   // prefetch K for next chunk
#pragma unroll
                for (int kt = 0; kt < 4; ++kt)
                    knxt[kt] = *(const uint4*)(kb + (MBp + kt0 + KC + kt * 16 + c) * CST + hg * 8);
            }
            const bool full = (kt0 + KC <= NN1);

            // ---- QK^T + softmax -> in-register P ----
            bf16x4 pa[2][4];
#pragma unroll
            for (int qt = 0; qt < 2; ++qt) {
                f32x4 Sf[4];
                __builtin_amdgcn_s_setprio(1);
#pragma unroll
                for (int kt = 0; kt < 4; ++kt)
                    Sf[kt] = __builtin_amdgcn_mfma_f32_16x16x32_bf16(
                        as_bf16x8(kcur[kt]), qf[qt], f32x4{0.f, 0.f, 0.f, 0.f}, 0, 0, 0);
                __builtin_amdgcn_s_setprio(0);

                if (!full) {   // mask pad keys (exp2(-3e38)==0)
#pragma unroll
                    for (int kt = 0; kt < 4; ++kt)
#pragma unroll
                        for (int r = 0; r < 4; ++r) {
                            int key = kt0 + kt * 16 + 4 * hg + r;
                            if (key >= NN1) Sf[kt][r] = -3.0e38f;
                        }
                }
                float psum = 0.f;
#pragma unroll
                for (int kt = 0; kt < 4; ++kt) {
                    float p0 = fexp2(Sf[kt][0]);
                    float p1 = fexp2(Sf[kt][1]);
                    float p2 = fexp2(Sf[kt][2]);
                    float p3 = fexp2(Sf[kt][3]);
                    psum += (p0 + p1) + (p2 + p3);
                    pa[qt][kt] = bf16x4{(__bf16)p0, (__bf16)p1, (__bf16)p2, (__bf16)p3};
                }
                lrun[qt] += psum;
            }

            // ---- V B-frags + PV via 16x16x16 ----
            bf16x4 vbf[2][4];
#pragma unroll
            for (int dt = 0; dt < 2; ++dt)
#pragma unroll
                for (int kt = 0; kt < 4; ++kt)
                    vbf[dt][kt] = *(const bf16x4*)&Vs[cur][sub][dt * 16 + c][kt * 16 + 4 * hg];

            __builtin_amdgcn_s_setprio(1);
#pragma unroll
            for (int qt = 0; qt < 2; ++qt)
#pragma unroll
                for (int dt = 0; dt < 2; ++dt)
#pragma unroll
                    for (int kt = 0; kt < 4; ++kt)
                        O[qt][dt] = mfma16(pa[qt][kt], vbf[dt][kt], O[qt][dt]);
            __builtin_amdgcn_s_setprio(0);

            if (haveK) {
#pragma unroll
                for (int kt = 0; kt < 4; ++kt) kcur[kt] = knxt[kt];
            }
        }

        if (havePair) {   // write next V pair into other buffer, one barrier
            union { uint4 u; unsigned short s[8]; } vu;
            vu.u = vr0;
#pragma unroll
            for (int j = 0; j < 8; ++j) Vs[cur ^ 1][0][k_col + j][k_row] = vu.s[j];
            vu.u = vr1;
#pragma unroll
            for (int j = 0; j < 8; ++j) Vs[cur ^ 1][1][k_col + j][k_row] = vu.s[j];
            __syncthreads();
        }
    }

    // epilogue: reduce partial l across hg groups, normalize, store
#pragma unroll
    for (int qt = 0; qt < 2; ++qt) {
        float Ls = lrun[qt];
        Ls += __shfl_xor(Ls, 16);
        Ls += __shfl_xor(Ls, 32);
#pragma unroll
        for (int r = 0; r < 4; ++r) {
            float lr_ = __shfl(Ls, 4 * hg + r);
            int row = q0 + qt * 16 + 4 * hg + r;
            float inv = (lr_ > 0.f) ? 1.0f / lr_ : 0.f;
            if (row < NN1) {
#pragma unroll
                for (int dt = 0; dt < 2; ++dt)
                    ao[((size_t)(b * NN1 + row)) * NC + hh * NHD + dt * 16 + c]
                        = (__bf16)(O[qt][dt][r] * inv);
            }
        }
    }
}

// ---------------------------------------------------------------------------
// Kernel 3: LePE depthwise 5x5 conv, 2 rows/thread (unchanged).
// ---------------------------------------------------------------------------
__global__ __launch_bounds__(256) void lepe2_k(
    const float* __restrict__ x, const float* __restrict__ wT,
    const float* __restrict__ bias, __bf16* __restrict__ ao)
{
    int idx = blockIdx.x * 256 + threadIdx.x;
    if (idx >= NB * (NHH / 2) * NWW * (NC / 4)) return;
    int cg = idx % (NC / 4);
    int c4 = cg * 4;
    int pos = idx / (NC / 4);
    int ww = pos % NWW;
    int hp = (pos / NWW) % (NHH / 2);
    int b = pos / (NWW * (NHH / 2));
    int hh = hp * 2;

    float4 bv = *(const float4*)(bias + c4);
    float a0[2], a1[2], a2[2], a3[2];
    a0[0] = bv.x; a1[0] = bv.y; a2[0] = bv.z; a3[0] = bv.w;
    a0[1] = bv.x; a1[1] = bv.y; a2[1] = bv.z; a3[1] = bv.w;

#pragma unroll
    for (int i = 0; i < 6; ++i) {
        int y = hh + i - 2;
        bool yv = (unsigned)y < NHH;
#pragma unroll
        for (int j = 0; j < 5; ++j) {
            int xw = ww + j - 2;
            if (yv && (unsigned)xw < NWW) {
                float4 xv = *(const float4*)(x + (((size_t)b * NHH + y) * NWW + xw) * NC + c4);
                if (i < 5) {
                    float4 wv = *(const float4*)(wT + (i * 5 + j) * NC + c4);
                    a0[0] += xv.x * wv.x; a1[0] += xv.y * wv.y;
                    a2[0] += xv.z * wv.z; a3[0] += xv.w * wv.w;
                }
                if (i >= 1) {
                    float4 wv = *(const float4*)(wT + ((i - 1) * 5 + j) * NC + c4);
                    a0[1] += xv.x * wv.x; a1[1] += xv.y * wv.y;
                    a2[1] += xv.z * wv.z; a3[1] += xv.w * wv.w;
                }
            }
        }
    }

#pragma unroll
    for (int rr = 0; rr < 2; ++rr) {
        size_t m = (size_t)b * NN1 + 1 + (hh + rr) * NWW + ww;
        uint2* aop = (uint2*)(ao + m * NC + c4);
        uint2 old = *aop;
        float r0 = a0[rr] + bf2f((unsigned short)(old.x & 0xffff));
        float r1 = a1[rr] + bf2f((unsigned short)(old.x >> 16));
        float r2 = a2[rr] + bf2f((unsigned short)(old.y & 0xffff));
        float r3 = a3[rr] + bf2f((unsigned short)(old.y >> 16));
        uint2 nw; nw.x = pack2(r0, r1); nw.y = pack2(r2, r3);
        *aop = nw;
    }
}

// ---------------------------------------------------------------------------
extern "C" void kernel_launch(void* const* d_in, const int* in_sizes, int n_in,
                              void* d_out, int out_size, void* d_ws, size_t ws_size,
                              hipStream_t stream)
{
    const float* x      = (const float*)d_in[0];
    const float* cls    = (const float*)d_in[1];
    const float* qkv_w  = (const float*)d_in[2];
    const float* proj_w = (const float*)d_in[3];
    const float* proj_b = (const float*)d_in[4];
    const float* lepe_w = (const float*)d_in[5];
    const float* lepe_b = (const float*)d_in[6];
    float* out = (float*)d_out;
    char*  ws  = (char*)d_ws;

    size_t off = 0;
    __bf16* Ab    = (__bf16*)(ws + off); off += (size_t)MP2 * NC * 2;
    __bf16* wqb   = (__bf16*)(ws + off); off += (size_t)1152 * NC * 2;
    __bf16* wpb   = (__bf16*)(ws + off); off += (size_t)NC * NC * 2;
    float*  lepeT = (float*) (ws + off); off += (size_t)25 * NC * 4;
    __bf16* Cg    = (__bf16*)(ws + off); off += (size_t)MP2 * CST * 2;
    __bf16* aob   = (__bf16*)(ws + off); off += (size_t)MPAD * NC * 2;

    {   // prep
        prep_k<<<(P_TOT + 255) / 256, 256, 0, stream>>>(
            x, cls, qkv_w, proj_w, lepe_w, Ab, wqb, wpb, lepeT, aob);
    }
    {   // QKV GEMM: gload_lds + swizzle, 1224 blocks
        qkv_mfma_k<<<9 * NMT, 256, 0, stream>>>(Ab, wqb, Cg);
    }
    {   // flash attention: 864 blocks, paired chunks (9 barriers)
        attn_mfma_k<<<9 * NBH, 256, 0, stream>>>(Cg, aob);
    }
    {   // LePE conv
        int total = NB * (NHW / 2) * (NC / 4);
        lepe2_k<<<(total + 255) / 256, 256, 0, stream>>>(x, lepeT, lepe_b, aob);
    }
    {   // projection GEMM
        proj_mfma_k<<<6 * 65, 256, 0, stream>>>(aob, wpb, proj_b, out);
    }
}